// Round 5
// baseline (159.697 us; speedup 1.0000x reference)
//
#include <hip/hip_runtime.h>
#include <stdint.h>

// RGCNConv: out = sum_r ((A * [edge==r]) @ x) @ W_r + bias
// N=4096, IN=OUT=256, R=8.
//   k_init : out[i][o] = bias[o]
//   k_y    : y_t[o][j*8+r] = (x @ W_r)[j][o]  (bf16, in ws, 16 MB)
//   k_main : expanded GEMM out[i][o] += sum_j A[i][j] * y_t[o][j*8+e[i][j]]
//            32x32x16 MFMA. A/et loaded per-lane direct to registers
//            (b128 = the 4 granule-j's a lane needs); B-only LDS, 3-deep
//            circular via global_load_lds, counted vmcnt(8), 1 barrier/step.

#define NN 4096

typedef __attribute__((ext_vector_type(8)))  short s16x8;   // 8 bf16 MFMA frag
typedef __attribute__((ext_vector_type(16))) float f32x16;  // 32x32 C/D
typedef __attribute__((ext_vector_type(4)))  float fx4;
typedef __attribute__((ext_vector_type(4)))  int   ix4;
typedef __attribute__((ext_vector_type(4)))  unsigned int ux4;

union uq { ux4 u; s16x8 s; };

__device__ __forceinline__ unsigned short f2bf(float f) {
  union { float f; unsigned int u; } v; v.f = f;
  unsigned int r = v.u + 0x7fffu + ((v.u >> 16) & 1u);  // RNE
  return (unsigned short)(r >> 16);
}

__device__ __forceinline__ void gld16(const void* g, void* l) {
  __builtin_amdgcn_global_load_lds(
      (const __attribute__((address_space(1))) unsigned int*)(uintptr_t)g,
      (__attribute__((address_space(3))) unsigned int*)(uintptr_t)l, 16, 0, 0);
}

// ---------------- init: out = bias ----------------
__global__ void k_init(const float* __restrict__ bias, float* __restrict__ out) {
  int idx = blockIdx.x * 256 + threadIdx.x;
  out[idx] = bias[idx & 255];
}

// ---------------- y_t[o][j*8+r] = sum_k x[j][k] * W[r][k][o] ----------------
__global__ __launch_bounds__(256, 2) void k_y(const float* __restrict__ x,
                                              const float* __restrict__ W,
                                              unsigned short* __restrict__ yt) {
  __shared__ unsigned short Wl[128 * 256];  // 64 KB
  const int t  = threadIdx.x;
  const int j0 = blockIdx.x * 128;
  const int o0 = blockIdx.y * 16;

  {
    const int r = t >> 5, kc = t & 31;
#pragma unroll
    for (int u = 0; u < 8; ++u) {
      const int k = kc * 8 + u;
      const fx4* wp = (const fx4*)(W + ((size_t)r * 256 + k) * 256 + o0);
      fx4 w[4] = { wp[0], wp[1], wp[2], wp[3] };
#pragma unroll
      for (int i = 0; i < 16; ++i) {
        const int row = i * 8 + r;               // n'
        const int gs  = (k >> 3) ^ (row & 7);    // swizzled 16B granule
        Wl[row * 256 + gs * 8 + (k & 7)] = f2bf(w[i >> 2][i & 3]);
      }
    }
  }
  __syncthreads();

  const int lane = t & 63, wid = t >> 6;
  const int l15 = lane & 15, lh = lane >> 4;
  const int npb = wid * 32;

  fx4 acc[8][2];
#pragma unroll
  for (int m = 0; m < 8; ++m)
#pragma unroll
    for (int n = 0; n < 2; ++n) acc[m][n] = 0.f;

  unsigned int qb[2];
#pragma unroll
  for (int n = 0; n < 2; ++n) {
    int row = npb + n * 16 + l15;
    qb[n] = (unsigned)(row * 512 + 16 * (lh ^ (row & 3))) ^ (64u * ((row >> 2) & 1));
  }
  const char* WlB = (const char*)Wl;
  const float* xb = x + (size_t)(j0 + l15) * 256 + lh * 8;

#pragma unroll
  for (int ks = 0; ks < 8; ++ks) {
    s16x8 a[8];
#pragma unroll
    for (int m = 0; m < 8; ++m) {
      const fx4* xp = (const fx4*)(xb + (size_t)m * 16 * 256 + ks * 32);
      fx4 x0 = xp[0], x1 = xp[1];
      s16x8 av;
#pragma unroll
      for (int i = 0; i < 4; ++i) av[i] = (short)f2bf(x0[i]);
#pragma unroll
      for (int i = 0; i < 4; ++i) av[4 + i] = (short)f2bf(x1[i]);
      a[m] = av;
    }
#pragma unroll
    for (int n = 0; n < 2; ++n) {
      s16x8 b = *(const s16x8*)(WlB + (qb[n] ^ (unsigned)(ks * 64)));
#pragma unroll
      for (int m = 0; m < 8; ++m)
        acc[m][n] = __builtin_amdgcn_mfma_f32_16x16x32_bf16(a[m], b, acc[m][n], 0, 0, 0);
    }
  }

#pragma unroll
  for (int m = 0; m < 8; ++m)
#pragma unroll
    for (int n = 0; n < 2; ++n)
#pragma unroll
      for (int q = 0; q < 4; ++q) {
        int jl = m * 16 + lh * 4 + q;
        int np = npb + n * 16 + l15;
        int o  = o0 + (np >> 3);
        yt[(size_t)o * 32768 + (size_t)(j0 + jl) * 8 + (np & 7)] = f2bf(acc[m][n][q]);
      }
}

// ---------------- main expanded GEMM ----------------
// grid (32 m, 2 n, 8 k) = 512 blocks (2/CU). Block 128x128, 4 waves (2x2),
// wave tile 64x64 via 32x32x16 MFMA (2 m-reps x 2 n-reps).
// Step = 8 j (K_eff 64 = 4 k-slices of 16). j(ks, half) = half*4 + ks.
// A/et: per-lane b128 direct loads (row = i0+wm*64+m*32+l31, j off lh1*4),
//       2-step register pipeline (even/odd sets).
// B: LDS 3 x (128 o x 8 slots x 16B) = 48 KB, global_load_lds with
//    source-swizzled granule (phys slot p holds j = p ^ (o&7)).
// Per step/thread: 8 VMEM (4 B-DMA + 2 A + 2 E). Steady: wait vmcnt(8),
// s_barrier, build frags, issue stage s+2, compute (never drain to 0).
__global__ __launch_bounds__(256, 2) void k_main(const float* __restrict__ A,
                                                 const int*   __restrict__ et,
                                                 const unsigned short* __restrict__ yt,
                                                 float* __restrict__ out) {
  __shared__ ux4 Bl[3 * 1024];  // 48 KB
  const int t = threadIdx.x, lane = t & 63, w = t >> 6;
  const int l31 = lane & 31, lh1 = lane >> 5;
  const int wm = w >> 1, wn = w & 1;
  const int i0 = blockIdx.x * 128;
  const int o0 = blockIdx.y * 128;
  const int jb = blockIdx.z * 512;

  // A/E per-lane direct sources (one fx4 = the 4 j's this lane needs)
  const fx4* pA[2]; const ix4* pE[2];
#pragma unroll
  for (int m = 0; m < 2; ++m) {
    size_t off = (size_t)(i0 + wm * 64 + m * 32 + l31) * NN + jb + lh1 * 4;
    pA[m] = (const fx4*)(A + off);
    pE[m] = (const ix4*)(et + off);
  }

  // B DMA sources (linear LDS dest, inverse-swizzled global granule)
  const ux4* ytg = (const ux4*)yt;  // [o][4096] 16B granules
  const ux4* sB[4];
#pragma unroll
  for (int u = 0; u < 4; ++u) {
    int row = w * 32 + u * 8 + (lane >> 3);
    int sl  = (lane & 7) ^ ((lane >> 3) & 7);
    sB[u] = ytg + ((size_t)(o0 + row) << 12) + jb + sl;
  }
  char* Bc = (char*)Bl;

  // B read offsets: byte = row*128 + ((lh1*4+ks)^(row&7))*16 = Qb[n] ^ (ks<<4)
  unsigned Qb[2];
#pragma unroll
  for (int n = 0; n < 2; ++n) {
    int row = wn * 64 + n * 32 + l31;
    Qb[n] = (unsigned)(row * 128 + (((lh1 * 4) ^ (row & 7)) << 4));
  }

  f32x16 acc[2][2];
#pragma unroll
  for (int m = 0; m < 2; ++m)
#pragma unroll
    for (int n = 0; n < 2; ++n) acc[m][n] = 0.f;

#define ISSUE(sq, p, aset, eset) do {                                   \
    _Pragma("unroll")                                                   \
    for (int u = 0; u < 4; ++u)                                         \
      gld16(sB[u] + (size_t)(sq) * 8,                                   \
            Bc + (p) * 16384 + (w * 32 + u * 8) * 128);                 \
    aset[0] = pA[0][(sq) * 2]; aset[1] = pA[1][(sq) * 2];               \
    eset[0] = pE[0][(sq) * 2]; eset[1] = pE[1][(sq) * 2];               \
  } while (0)

#define BUILD(aset, eset, frag) do {                                    \
    _Pragma("unroll")                                                   \
    for (int m = 0; m < 2; ++m)                                         \
      _Pragma("unroll")                                                 \
      for (int ks = 0; ks < 4; ++ks) {                                  \
        unsigned hv = f2bf(aset[m][ks]);                                \
        int ev = eset[m][ks];                                           \
        unsigned long long sh = ((unsigned long long)hv) << ((ev & 3) * 16); \
        unsigned lo = (unsigned)sh, hi = (unsigned)(sh >> 32);          \
        bool c = ev < 4;                                                \
        ux4 q;                                                          \
        q.x = c ? lo : 0u; q.y = c ? hi : 0u;                           \
        q.z = c ? 0u : lo; q.w = c ? 0u : hi;                           \
        frag[m][ks].u = q;                                              \
      }                                                                 \
  } while (0)

#define COMPUTE(p, frag) do {                                           \
    const unsigned pB = (unsigned)((p) * 16384);                        \
    _Pragma("unroll")                                                   \
    for (int ks = 0; ks < 4; ++ks) {                                    \
      uq b0, b1;                                                        \
      b0.u = *(const ux4*)(Bc + pB + (Qb[0] ^ (unsigned)(ks << 4)));    \
      b1.u = *(const ux4*)(Bc + pB + (Qb[1] ^ (unsigned)(ks << 4)));    \
      _Pragma("unroll")                                                 \
      for (int m = 0; m < 2; ++m) {                                     \
        acc[m][0] = __builtin_amdgcn_mfma_f32_32x32x16_bf16(frag[m][ks].s, b0.s, acc[m][0], 0, 0, 0); \
        acc[m][1] = __builtin_amdgcn_mfma_f32_32x32x16_bf16(frag[m][ks].s, b1.s, acc[m][1], 0, 0, 0); \
      }                                                                 \
    }                                                                   \
  } while (0)

  fx4 aE[2], aO[2]; ix4 eE[2], eO[2];
  uq fragE[2][4], fragO[2][4];

  // prologue: 2 stages in flight
  ISSUE(0, 0, aE, eE);
  ISSUE(1, 1, aO, eO);

  int p = 0;  // buffer of current (even) step
  for (int s = 0; s < 64; s += 2) {
    int p1 = p + 1; if (p1 == 3) p1 = 0;
    int p2 = p + 2; if (p2 >= 3) p2 -= 3;
    int sq2 = (s + 2 > 63) ? 63 : s + 2;
    int sq3 = (s + 3 > 63) ? 63 : s + 3;
    // ---- even step s ----
    asm volatile("s_waitcnt vmcnt(8)" ::: "memory");  // stage s landed
    __builtin_amdgcn_s_barrier();                     // all waves' stage s visible
    BUILD(aE, eE, fragE);
    ISSUE(sq2, p2, aE, eE);                           // buf(s-1): freed by barrier
    COMPUTE(p, fragE);
    // ---- odd step s+1 ----
    asm volatile("s_waitcnt vmcnt(8)" ::: "memory");
    __builtin_amdgcn_s_barrier();
    BUILD(aO, eO, fragO);
    ISSUE(sq3, p, aO, eO);
    COMPUTE(p1, fragO);
    p = p2;
  }
  asm volatile("s_waitcnt vmcnt(0)" ::: "memory");  // drain DMA before exit

  // epilogue: K-split partial accumulate.
  // 32x32 C layout: col = l31, row = (reg&3) + 8*(reg>>2) + 4*lh1
#pragma unroll
  for (int m = 0; m < 2; ++m)
#pragma unroll
    for (int n = 0; n < 2; ++n)
#pragma unroll
      for (int q = 0; q < 16; ++q) {
        int gi = i0 + wm * 64 + m * 32 + (q & 3) + 8 * (q >> 2) + 4 * lh1;
        int go = o0 + wn * 64 + n * 32 + l31;
        atomicAdd(out + (size_t)gi * 256 + go, acc[m][n][q]);
      }
#undef ISSUE
#undef BUILD
#undef COMPUTE
}

extern "C" void kernel_launch(void* const* d_in, const int* in_sizes, int n_in,
                              void* d_out, int out_size, void* d_ws, size_t ws_size,
                              hipStream_t stream) {
  const float* x    = (const float*)d_in[0];
  const float* A    = (const float*)d_in[1];
  const int*   et   = (const int*)d_in[2];
  const float* W    = (const float*)d_in[3];
  const float* bias = (const float*)d_in[4];
  float* out = (float*)d_out;
  unsigned short* yt = (unsigned short*)d_ws;  // 16 MB

  k_init<<<dim3(4096), dim3(256), 0, stream>>>(bias, out);
  k_y   <<<dim3(32, 16), dim3(256), 0, stream>>>(x, W, yt);
  k_main<<<dim3(32, 2, 8), dim3(256), 0, stream>>>(A, et, yt, out);
}